// Round 4
// baseline (136.069 us; speedup 1.0000x reference)
//
#include <hip/hip_runtime.h>
#include <hip/hip_bf16.h>

typedef short short8 __attribute__((ext_vector_type(8)));
typedef unsigned int u32x4 __attribute__((ext_vector_type(4)));
typedef float f32x4 __attribute__((ext_vector_type(4)));
typedef float f32x2 __attribute__((ext_vector_type(2)));

#define SPAT  32768
#define KPROD 27

// ---- prep 1: x [64][32768] f32 -> xt [32768][64] bf16 (128B rows) ----
__global__ void transpose_x_bf16(const float* __restrict__ x, unsigned short* __restrict__ xt) {
    __shared__ float tile[64][65];
    const int t = threadIdx.x;
    const int s0 = blockIdx.x * 64;
    const int lane = t & 63, grp = t >> 6;
#pragma unroll
    for (int r = 0; r < 16; ++r) {
        int c = grp * 16 + r;
        tile[c][lane] = x[c * SPAT + s0 + lane];
    }
    __syncthreads();
#pragma unroll
    for (int r = 0; r < 16; ++r) {
        int srow = grp * 16 + r;
        xt[(s0 + srow) * 64 + lane] = __bfloat16_as_ushort(__float2bfloat16(tile[lane][srow]));
    }
}

// ---- prep 2: weight [o][c][k] f32 -> A-fragments wf[k][i=ot*2+kb][lane][e] bf16 ----
__global__ void prep_w_frag(const float* __restrict__ w, unsigned short* __restrict__ wt) {
    int idx = blockIdx.x * 256 + threadIdx.x;
    if (idx >= KPROD * 4096) return;
    int k = idx >> 12;
    int fid = idx & 4095;
    int i = fid >> 9;                 // ot*2+kb
    int lane = (fid >> 3) & 63;
    int e = fid & 7;
    int ot = i >> 1, kb = i & 1;
    int o = ot * 16 + (lane & 15);
    int c = kb * 32 + (lane >> 4) * 8 + e;
    wt[idx] = __bfloat16_as_ushort(__float2bfloat16(w[(o * 64 + c) * KPROD + k]));
}

// ---- main: 3 waves/block, each wave = 9 taps of the same 16 positions ----
__global__ __launch_bounds__(192)
void dconv3d_wave3(const unsigned short* __restrict__ xt, const unsigned short* __restrict__ wf,
                   const float* __restrict__ offset, const float* __restrict__ mask,
                   float* __restrict__ out) {
    __shared__ float meta_w[3][2][8][24];   // per-wave buffers, stride 24 (2-way max = free)
    __shared__ int   meta_o[3][2][8][24];
    __shared__ float red[16][66];           // reduction buffer, padded

    const int t   = threadIdx.x;
    const int wid = t >> 6;              // wave id: owns taps [wid*9, wid*9+9)
    const int l   = t & 63;
    const int pl  = l & 15;              // my output position (within tile)
    const int g   = l >> 4;              // quad group / k-slice
    const int g16 = g * 16;

    // bijective XCD swizzle (2048 % 8 == 0): neighbor tiles share an XCD L2
    const int nwg = (int)gridDim.x;
    const int cpx = nwg >> 3;
    const int bid = (int)blockIdx.x;
    const int bsw = (bid % 8) * cpx + (bid / 8);

    const int p_base = bsw * 16;
    const int pos = p_base + pl;
    const int ho = pos >> 10, wo = (pos >> 5) & 31, lo = pos & 31;
    const char* xbase = (const char*)xt;
    const int k0 = wid * 9;

    f32x4 acc[4] = {};

    auto compute_meta = [&](int k, int buf) {
        float oh = offset[(3 * k + 0) * SPAT + pos];
        float ow = offset[(3 * k + 1) * SPAT + pos];
        float ol = offset[(3 * k + 2) * SPAT + pos];
        float mk = mask[k * SPAT + pos];
        int ki = k / 9, kj = (k / 3) % 3, kk = k % 3;
        float chh = oh + (float)(ho - 1 + ki);
        float cww = ow + (float)(wo - 1 + kj);
        float cll = ol + (float)(lo - 1 + kk);
        float h0f = floorf(chh), w0f = floorf(cww), l0f = floorf(cll);
        float fh = chh - h0f, fw = cww - w0f, fl = cll - l0f;
        int h0 = (int)h0f, w0 = (int)w0f, l0i = (int)l0f;
#pragma unroll
        for (int jj = 0; jj < 2; ++jj) {
            int j = g * 2 + jj;          // this lane owns 2 corners of its p
            int dh = j >> 2, dw = (j >> 1) & 1, dl = j & 1;
            int ih = h0 + dh, iw = w0 + dw, il = l0i + dl;
            float wh = dh ? fh : 1.f - fh;
            float ww = dw ? fw : 1.f - fw;
            float wl = dl ? fl : 1.f - fl;
            bool valid = (unsigned)ih < 32u && (unsigned)iw < 32u && (unsigned)il < 32u;
            float wvv = valid ? wh * ww * wl * mk : 0.f;
            int ihc = min(max(ih, 0), 31);
            int iwc = min(max(iw, 0), 31);
            int ilc = min(max(il, 0), 31);
            int lin = (ihc * 32 + iwc) * 32 + ilc;
            meta_w[wid][buf][j][pl] = wvv;
            meta_o[wid][buf][j][pl] = lin * 128;   // byte offset of bf16 row
        }
    };

    // ---- prologue: meta(k0) + W-frags(k0) ----
    compute_meta(k0, 0);
    float mw[8]; int mo[8];
#pragma unroll
    for (int j = 0; j < 8; ++j) { mw[j] = meta_w[wid][0][j][pl]; mo[j] = meta_o[wid][0][j][pl]; }
    short8 wfr[8];
#pragma unroll
    for (int i = 0; i < 8; ++i) wfr[i] = *(const short8*)&wf[((size_t)k0 * 8 + i) * 512 + l * 8];

#pragma unroll 1
    for (int kk = 0; kk < 9; ++kk) {
        const int k  = k0 + kk;
        const int kn = (kk + 1 < 9) ? k + 1 : k;
        const int bufn = (kk + 1) & 1;

        // 1. issue all 16 gathers for tap k
        u32x4 q0[8], q1[8];
#pragma unroll
        for (int j = 0; j < 8; ++j) {
            const char* rowp = xbase + (mo[j] + g16);
            q0[j] = *(const u32x4*)rowp;          // c-octet, kb=0
            q1[j] = *(const u32x4*)(rowp + 64);   // c-octet, kb=1
        }

        // 2. overlap: meta for tap k+1
        compute_meta(kn, bufn);

        // 3. consume gathers: trilinear accumulate (float2 -> v_pk_fma_f32)
        f32x2 v0[4] = {}, v1[4] = {};
#pragma unroll
        for (int j = 0; j < 8; ++j) {
            f32x2 w2 = {mw[j], mw[j]};
#pragma unroll
            for (int q = 0; q < 4; ++q) {
                unsigned int a = q0[j][q];
                unsigned int b = q1[j][q];
                f32x2 xa = {__uint_as_float(a << 16), __uint_as_float(a & 0xffff0000u)};
                f32x2 xb = {__uint_as_float(b << 16), __uint_as_float(b & 0xffff0000u)};
                v0[q] = __builtin_elementwise_fma(w2, xa, v0[q]);
                v1[q] = __builtin_elementwise_fma(w2, xb, v1[q]);
            }
        }

        // 4. B-fragments (bf16)
        short8 b0, b1;
#pragma unroll
        for (int q = 0; q < 4; ++q) {
            b0[2*q]   = (short)__bfloat16_as_ushort(__float2bfloat16(v0[q].x));
            b0[2*q+1] = (short)__bfloat16_as_ushort(__float2bfloat16(v0[q].y));
            b1[2*q]   = (short)__bfloat16_as_ushort(__float2bfloat16(v1[q].x));
            b1[2*q+1] = (short)__bfloat16_as_ushort(__float2bfloat16(v1[q].y));
        }

        // 5. prefetch W-frags for k+1
        short8 wfn[8];
#pragma unroll
        for (int i = 0; i < 8; ++i) wfn[i] = *(const short8*)&wf[((size_t)kn * 8 + i) * 512 + l * 8];

        // 6. MFMA: 64o x 16p, K=64
#pragma unroll
        for (int ot = 0; ot < 4; ++ot) {
            acc[ot] = __builtin_amdgcn_mfma_f32_16x16x32_bf16(wfr[ot*2+0], b0, acc[ot], 0, 0, 0);
            acc[ot] = __builtin_amdgcn_mfma_f32_16x16x32_bf16(wfr[ot*2+1], b1, acc[ot], 0, 0, 0);
        }

        // 7. pull meta(k+1) into regs; rotate W
#pragma unroll
        for (int j = 0; j < 8; ++j) { mw[j] = meta_w[wid][bufn][j][pl]; mo[j] = meta_o[wid][bufn][j][pl]; }
#pragma unroll
        for (int i = 0; i < 8; ++i) wfr[i] = wfn[i];
    }

    // ---- barrier-ordered reduction across the 3 waves (deterministic) ----
    // D layout: col = lane&15 (p), row = g*4+r (o within 16-block)
    __syncthreads();
    if (wid == 0) {
#pragma unroll
        for (int ot = 0; ot < 4; ++ot)
#pragma unroll
            for (int r = 0; r < 4; ++r)
                red[pl][ot * 16 + g * 4 + r] = acc[ot][r];
    }
    __syncthreads();
    if (wid == 1) {
#pragma unroll
        for (int ot = 0; ot < 4; ++ot)
#pragma unroll
            for (int r = 0; r < 4; ++r)
                red[pl][ot * 16 + g * 4 + r] += acc[ot][r];
    }
    __syncthreads();
    if (wid == 2) {
#pragma unroll
        for (int ot = 0; ot < 4; ++ot)
#pragma unroll
            for (int r = 0; r < 4; ++r)
                red[pl][ot * 16 + g * 4 + r] += acc[ot][r];
    }
    __syncthreads();

    // ---- coalesced-ish store: 16-wide p runs per o ----
    for (int idx = t; idx < 1024; idx += 192) {
        int p = idx & 15, o = idx >> 4;
        out[(size_t)o * SPAT + p_base + p] = red[p][o];
    }
}

extern "C" void kernel_launch(void* const* d_in, const int* in_sizes, int n_in,
                              void* d_out, int out_size, void* d_ws, size_t ws_size,
                              hipStream_t stream) {
    const float* x      = (const float*)d_in[0];
    const float* offset = (const float*)d_in[1];
    const float* mask   = (const float*)d_in[2];
    const float* weight = (const float*)d_in[3];
    float* out = (float*)d_out;

    unsigned short* xt  = (unsigned short*)d_ws;                                  // 4 MB
    unsigned short* wtb = (unsigned short*)((char*)d_ws + (size_t)SPAT * 64 * 2); // 216 KB

    hipLaunchKernelGGL(transpose_x_bf16, dim3(SPAT / 64), dim3(256), 0, stream, x, xt);
    hipLaunchKernelGGL(prep_w_frag, dim3((KPROD * 4096 + 255) / 256), dim3(256), 0, stream,
                       weight, wtb);
    hipLaunchKernelGGL(dconv3d_wave3, dim3(SPAT / 16), dim3(192), 0, stream,
                       xt, wtb, offset, mask, out);
}